// Round 8
// baseline (686.304 us; speedup 1.0000x reference)
//
#include <hip/hip_runtime.h>

#define N_NODES 100000
#define N_EDGES 1600000
#define D_IN 128
#define D 64

#define NBLK 1000          // scatter blocks
#define EPB  1600          // edges per scatter block (NBLK*EPB == N_EDGES)
#define NB2  391           // coarse buckets: dst>>8, max 99999>>8 = 390
#define SC_M  (NB2 * NBLK)                  // 391,000 scan elements
#define SC_CH 1024                          // elements per scan chunk
#define SC_NB ((SC_M + SC_CH - 1) / SC_CH)  // 382 chunks

__device__ __forceinline__ float bflo(unsigned int u) {
    union { unsigned int i; float f; } q; q.i = u << 16; return q.f;
}
__device__ __forceinline__ float bfhi(unsigned int u) {
    union { unsigned int i; float f; } q; q.i = u & 0xFFFF0000u; return q.f;
}
__device__ __forceinline__ unsigned short f2bf(float f) {
    unsigned int u = __float_as_uint(f);
    unsigned int r = (u + 0x7FFFu + ((u >> 16) & 1u)) >> 16;   // RNE
    return (unsigned short)r;
}
__device__ __forceinline__ void accU4(float* a, uint4 v) {
    a[0] += bflo(v.x); a[1] += bfhi(v.x);
    a[2] += bflo(v.y); a[3] += bfhi(v.y);
    a[4] += bflo(v.z); a[5] += bfhi(v.z);
    a[6] += bflo(v.w); a[7] += bfhi(v.w);
}

// ============ CSR build: two-level counting sort, LDS atomics only ============

__global__ __launch_bounds__(256) void k_hist1(const int* __restrict__ dst,
                                               int* __restrict__ bh) {
    __shared__ int h[NB2];
    int t = threadIdx.x;
    for (int i = t; i < NB2; i += 256) h[i] = 0;
    __syncthreads();
    int base = blockIdx.x * EPB;
    for (int i = t; i < EPB; i += 256) atomicAdd(&h[dst[base + i] >> 8], 1);
    __syncthreads();
    for (int i = t; i < NB2; i += 256) bh[i * NBLK + blockIdx.x] = h[i];
}

__global__ __launch_bounds__(256) void k_scanA(const int* __restrict__ bh,
                                               int* __restrict__ part) {
    __shared__ int s[256];
    int t = threadIdx.x;
    int base = blockIdx.x * SC_CH + t * 4;
    int sum = 0;
    if (base + 3 < SC_M) {
        int4 v = *(const int4*)(bh + base);
        sum = (v.x + v.y) + (v.z + v.w);
    } else {
        for (int k = 0; k < 4; k++) if (base + k < SC_M) sum += bh[base + k];
    }
    s[t] = sum;
    __syncthreads();
    for (int o = 128; o > 0; o >>= 1) {
        if (t < o) s[t] += s[t + o];
        __syncthreads();
    }
    if (t == 0) part[blockIdx.x] = s[0];
}

__global__ __launch_bounds__(512) void k_scanB(int* __restrict__ part) {
    __shared__ int s[512];
    int t = threadIdx.x;
    int v = (t < SC_NB) ? part[t] : 0;
    s[t] = v;
    __syncthreads();
    for (int o = 1; o < 512; o <<= 1) {
        int x = (t >= o) ? s[t - o] : 0;
        __syncthreads();
        s[t] += x;
        __syncthreads();
    }
    if (t < SC_NB) part[t] = s[t] - v;   // exclusive
}

__global__ __launch_bounds__(256) void k_scanC(int* __restrict__ bh,
                                               const int* __restrict__ part) {
    __shared__ int s[256];
    int t = threadIdx.x;
    int base = blockIdx.x * SC_CH + t * 4;
    int4 v = {0, 0, 0, 0};
    if (base + 3 < SC_M) v = *(const int4*)(bh + base);
    else { for (int k = 0; k < 4; k++) if (base + k < SC_M) (&v.x)[k] = bh[base + k]; }
    int sum = (v.x + v.y) + (v.z + v.w);
    s[t] = sum;
    __syncthreads();
    for (int o = 1; o < 256; o <<= 1) {
        int x = (t >= o) ? s[t - o] : 0;
        __syncthreads();
        s[t] += x;
        __syncthreads();
    }
    int run = part[blockIdx.x] + s[t] - sum;
    int4 w;
    w.x = run; run += v.x;
    w.y = run; run += v.y;
    w.z = run; run += v.z;
    w.w = run;
    if (base + 3 < SC_M) *(int4*)(bh + base) = w;
    else { for (int k = 0; k < 4; k++) if (base + k < SC_M) bh[base + k] = (&w.x)[k]; }
}

__global__ __launch_bounds__(256) void k_scatter1(const int* __restrict__ src,
                                                  const int* __restrict__ dst,
                                                  const int* __restrict__ bh,
                                                  uint2* __restrict__ tmp) {
    __shared__ int cur[NB2];
    int t = threadIdx.x;
    for (int i = t; i < NB2; i += 256) cur[i] = bh[i * NBLK + blockIdx.x];
    __syncthreads();
    int base = blockIdx.x * EPB;
    for (int i = t; i < EPB; i += 256) {
        int d = dst[base + i];
        int sv = src[base + i];
        int p = atomicAdd(&cur[d >> 8], 1);
        tmp[p] = make_uint2((unsigned)d, (unsigned)sv);
    }
}

// B1: per-bucket node degrees + padded (multiple-of-8) bucket sums
__global__ __launch_bounds__(256) void k_padsum(const uint2* __restrict__ tmp,
                                                const int* __restrict__ bh,
                                                int* __restrict__ degarr,
                                                int* __restrict__ pb) {
    __shared__ int deg[256];
    __shared__ int s[256];
    int b = blockIdx.x, t = threadIdx.x;
    int e0 = bh[b * NBLK];
    int e1 = (b == NB2 - 1) ? N_EDGES : bh[(b + 1) * NBLK];
    deg[t] = 0;
    __syncthreads();
    for (int i = e0 + t; i < e1; i += 256) atomicAdd(&deg[tmp[i].x & 255u], 1);
    __syncthreads();
    int node = b * 256 + t;
    int d = (node < N_NODES) ? deg[t] : 0;
    if (node < N_NODES) degarr[node] = d;
    int dp = (d + 7) & ~7;
    s[t] = dp;
    __syncthreads();
    for (int o = 128; o > 0; o >>= 1) {
        if (t < o) s[t] += s[t + o];
        __syncthreads();
    }
    if (t == 0) pb[b] = s[0];
}

__global__ __launch_bounds__(512) void k_scanP(int* __restrict__ pb) {
    __shared__ int s[512];
    int t = threadIdx.x;
    int v = (t < NB2) ? pb[t] : 0;
    s[t] = v;
    __syncthreads();
    for (int o = 1; o < 512; o <<= 1) {
        int x = (t >= o) ? s[t - o] : 0;
        __syncthreads();
        s[t] += x;
        __syncthreads();
    }
    if (t < NB2) pb[t] = s[t] - v;   // exclusive
}

// B3: padded CSR build (pad slots -> N_NODES = zero row)
__global__ __launch_bounds__(256) void k_build2(const uint2* __restrict__ tmp,
                                                const int* __restrict__ bh,
                                                const int* __restrict__ degarr,
                                                const int* __restrict__ pb,
                                                int* __restrict__ offs,
                                                int* __restrict__ csr) {
    __shared__ int s[256];
    __shared__ int startp[256];
    __shared__ int cur[256];
    int b = blockIdx.x, t = threadIdx.x;
    int e0 = bh[b * NBLK];
    int e1 = (b == NB2 - 1) ? N_EDGES : bh[(b + 1) * NBLK];
    int node = b * 256 + t;
    int d = (node < N_NODES) ? degarr[node] : 0;
    int dp = (d + 7) & ~7;
    s[t] = dp;
    __syncthreads();
    for (int o = 1; o < 256; o <<= 1) {
        int x = (t >= o) ? s[t - o] : 0;
        __syncthreads();
        s[t] += x;
        __syncthreads();
    }
    int st = pb[b] + s[t] - dp;
    startp[t] = st;
    cur[t] = st;
    if (node < N_NODES) {
        offs[node] = st;
        if (node == N_NODES - 1) offs[N_NODES] = st + dp;
    }
    __syncthreads();
    for (int i = e0 + t; i < e1; i += 256) {
        uint2 p = tmp[i];
        int pos = atomicAdd(&cur[p.x & 255u], 1);
        csr[pos] = (int)p.y;
    }
    __syncthreads();
    int end = startp[t] + dp;
    for (int p = cur[t]; p < end; p++) csr[p] = N_NODES;   // zero-row index
}

// ---------------- z = x @ w1a  (128 -> 64, no bias), z stored bf16 ----------------
__global__ __launch_bounds__(256) void k_gemm1(const float* __restrict__ x,
                                               const float* __restrict__ w,
                                               unsigned short* __restrict__ z) {
    __shared__ float ws[D_IN][D];        // 32 KB
    __shared__ float xs[16][D_IN + 1];
    int t = threadIdx.x;
    {
        const float4* w4 = (const float4*)w;
        float4* s4 = (float4*)&ws[0][0];
        for (int i = t; i < (D_IN * D) / 4; i += 256) s4[i] = w4[i];
    }
    int r = t >> 4, c = t & 15;
    __syncthreads();
    for (int base = blockIdx.x * 16; base < N_NODES; base += gridDim.x * 16) {
        for (int i = t; i < 16 * (D_IN / 4); i += 256) {
            int row = i >> 5, k4 = i & 31;
            float4 v = ((const float4*)(x + (size_t)(base + row) * D_IN))[k4];
            xs[row][k4 * 4 + 0] = v.x; xs[row][k4 * 4 + 1] = v.y;
            xs[row][k4 * 4 + 2] = v.z; xs[row][k4 * 4 + 3] = v.w;
        }
        __syncthreads();
        float4 acc = {0.f, 0.f, 0.f, 0.f};
        for (int k = 0; k < D_IN; k++) {
            float xv = xs[r][k];
            float4 wv = *(const float4*)&ws[k][c * 4];
            acc.x += xv * wv.x; acc.y += xv * wv.y;
            acc.z += xv * wv.z; acc.w += xv * wv.w;
        }
        ushort4 p;
        p.x = f2bf(acc.x); p.y = f2bf(acc.y); p.z = f2bf(acc.z); p.w = f2bf(acc.w);
        *(ushort4*)(z + (size_t)(base + r) * D + c * 4) = p;
        __syncthreads();
    }
}

// padded depth-8 gather, 16 B/lane: one vmem instruction covers 8 rows/wave
__device__ __forceinline__ void gather8p(float* acc, const unsigned short* __restrict__ zz,
                                         const int* __restrict__ csr,
                                         int e0, int e1, int c) {
    const char* zb = (const char*)zz;
    for (int e = e0; e < e1; e += 8) {
        int idx[8];
        *(int4*)(&idx[0]) = *(const int4*)(csr + e);
        *(int4*)(&idx[4]) = *(const int4*)(csr + e + 4);
        uint4 vv[8];
        #pragma unroll
        for (int k = 0; k < 8; k++)
            vv[k] = *(const uint4*)(zb + (size_t)idx[k] * 128 + c * 16);
        #pragma unroll
        for (int k = 0; k < 8; k++) accU4(acc, vv[k]);
    }
}

// ---------------- conv1 fused: agg(z)+b1a+relu, @w1b+b1b relu, @w2a -> u (bf16) ----------------
// 8 lanes/node, 32 nodes/block. LDS: 16 KB weights + 17.4 KB h -> 4 blocks/CU.
#define HS 68   // h row stride (floats): 16-B aligned, conflict-free broadcast
__global__ __launch_bounds__(256, 4) void k_conv1(const unsigned short* __restrict__ z,
                                                  const int* __restrict__ offs,
                                                  const int* __restrict__ csr,
                                                  const float* __restrict__ b1a,
                                                  const float* __restrict__ w1b,
                                                  const float* __restrict__ b1b,
                                                  const float* __restrict__ w2a,
                                                  unsigned short* __restrict__ u) {
    __shared__ unsigned short w1s[D][D];   // 8 KB bf16
    __shared__ unsigned short w2s[D][D];   // 8 KB bf16
    __shared__ float h1s[32][HS];
    __shared__ float h2s[32][HS];
    int t = threadIdx.x;
    int r = t >> 3, c = t & 7;
    {
        for (int i = t; i < (D * D) / 4; i += 256) {
            float4 a = ((const float4*)w1b)[i];
            ushort4 p; p.x = f2bf(a.x); p.y = f2bf(a.y); p.z = f2bf(a.z); p.w = f2bf(a.w);
            *(ushort4*)&(&w1s[0][0])[i * 4] = p;
            float4 b = ((const float4*)w2a)[i];
            ushort4 q; q.x = f2bf(b.x); q.y = f2bf(b.y); q.z = f2bf(b.z); q.w = f2bf(b.w);
            *(ushort4*)&(&w2s[0][0])[i * 4] = q;
        }
    }
    float vb1a[8], vb1b[8];
    {
        float4 a0 = ((const float4*)b1a)[c * 2], a1 = ((const float4*)b1a)[c * 2 + 1];
        vb1a[0] = a0.x; vb1a[1] = a0.y; vb1a[2] = a0.z; vb1a[3] = a0.w;
        vb1a[4] = a1.x; vb1a[5] = a1.y; vb1a[6] = a1.z; vb1a[7] = a1.w;
        float4 b0 = ((const float4*)b1b)[c * 2], b1 = ((const float4*)b1b)[c * 2 + 1];
        vb1b[0] = b0.x; vb1b[1] = b0.y; vb1b[2] = b0.z; vb1b[3] = b0.w;
        vb1b[4] = b1.x; vb1b[5] = b1.y; vb1b[6] = b1.z; vb1b[7] = b1.w;
    }
    __syncthreads();

    for (int base = blockIdx.x * 32; base < N_NODES; base += gridDim.x * 32) {
        int node = base + r;   // N_NODES % 32 == 0
        float acc[8];
        #pragma unroll
        for (int j = 0; j < 8; j++) acc[j] = vb1a[j];
        accU4(acc, *(const uint4*)((const char*)z + (size_t)node * 128 + c * 16));
        int e0 = offs[node], e1 = offs[node + 1];
        gather8p(acc, z, csr, e0, e1, c);
        *(float4*)&h1s[r][c * 8]     = make_float4(fmaxf(acc[0], 0.f), fmaxf(acc[1], 0.f),
                                                   fmaxf(acc[2], 0.f), fmaxf(acc[3], 0.f));
        *(float4*)&h1s[r][c * 8 + 4] = make_float4(fmaxf(acc[4], 0.f), fmaxf(acc[5], 0.f),
                                                   fmaxf(acc[6], 0.f), fmaxf(acc[7], 0.f));
        __syncthreads();
        // --- h2 = relu(h1 @ w1b + b1b) ---
        float a2[8];
        #pragma unroll
        for (int j = 0; j < 8; j++) a2[j] = vb1b[j];
        for (int k = 0; k < D; k++) {
            float hv = h1s[r][k];
            uint4 w = *(const uint4*)&w1s[k][c * 8];
            a2[0] += hv * bflo(w.x); a2[1] += hv * bfhi(w.x);
            a2[2] += hv * bflo(w.y); a2[3] += hv * bfhi(w.y);
            a2[4] += hv * bflo(w.z); a2[5] += hv * bfhi(w.z);
            a2[6] += hv * bflo(w.w); a2[7] += hv * bfhi(w.w);
        }
        *(float4*)&h2s[r][c * 8]     = make_float4(fmaxf(a2[0], 0.f), fmaxf(a2[1], 0.f),
                                                   fmaxf(a2[2], 0.f), fmaxf(a2[3], 0.f));
        *(float4*)&h2s[r][c * 8 + 4] = make_float4(fmaxf(a2[4], 0.f), fmaxf(a2[5], 0.f),
                                                   fmaxf(a2[6], 0.f), fmaxf(a2[7], 0.f));
        __syncthreads();
        // --- u = h2 @ w2a  (bias b2a applied in conv2 agg), u stored bf16 ---
        float a3[8] = {0.f, 0.f, 0.f, 0.f, 0.f, 0.f, 0.f, 0.f};
        for (int k = 0; k < D; k++) {
            float hv = h2s[r][k];
            uint4 w = *(const uint4*)&w2s[k][c * 8];
            a3[0] += hv * bflo(w.x); a3[1] += hv * bfhi(w.x);
            a3[2] += hv * bflo(w.y); a3[3] += hv * bfhi(w.y);
            a3[4] += hv * bflo(w.z); a3[5] += hv * bfhi(w.z);
            a3[6] += hv * bflo(w.w); a3[7] += hv * bfhi(w.w);
        }
        uint4 p;
        p.x = ((unsigned)f2bf(a3[1]) << 16) | f2bf(a3[0]);
        p.y = ((unsigned)f2bf(a3[3]) << 16) | f2bf(a3[2]);
        p.z = ((unsigned)f2bf(a3[5]) << 16) | f2bf(a3[4]);
        p.w = ((unsigned)f2bf(a3[7]) << 16) | f2bf(a3[6]);
        *(uint4*)((char*)u + (size_t)node * 128 + c * 16) = p;
        __syncthreads();
    }
}

// ---------------- conv2 fused: agg(u) + b2a + relu -> column sum ----------------
__global__ __launch_bounds__(256, 6) void k_conv2(const unsigned short* __restrict__ u,
                                                  const int* __restrict__ offs,
                                                  const int* __restrict__ csr,
                                                  const float* __restrict__ b2a,
                                                  float* __restrict__ colsum) {
    __shared__ float red[32][HS];
    int t = threadIdx.x;
    int r = t >> 3, c = t & 7;
    float vb[8];
    {
        float4 a0 = ((const float4*)b2a)[c * 2], a1 = ((const float4*)b2a)[c * 2 + 1];
        vb[0] = a0.x; vb[1] = a0.y; vb[2] = a0.z; vb[3] = a0.w;
        vb[4] = a1.x; vb[5] = a1.y; vb[6] = a1.z; vb[7] = a1.w;
    }
    float cs[8] = {0.f, 0.f, 0.f, 0.f, 0.f, 0.f, 0.f, 0.f};
    for (int base = blockIdx.x * 32; base < N_NODES; base += gridDim.x * 32) {
        int node = base + r;
        float acc[8];
        #pragma unroll
        for (int j = 0; j < 8; j++) acc[j] = vb[j];
        accU4(acc, *(const uint4*)((const char*)u + (size_t)node * 128 + c * 16));
        int e0 = offs[node], e1 = offs[node + 1];
        gather8p(acc, u, csr, e0, e1, c);
        #pragma unroll
        for (int j = 0; j < 8; j++) cs[j] += fmaxf(acc[j], 0.f);
    }
    *(float4*)&red[r][c * 8]     = make_float4(cs[0], cs[1], cs[2], cs[3]);
    *(float4*)&red[r][c * 8 + 4] = make_float4(cs[4], cs[5], cs[6], cs[7]);
    for (int off = 16; off >= 1; off >>= 1) {
        __syncthreads();
        if (r < off) {
            #pragma unroll
            for (int j = 0; j < 8; j++) red[r][c * 8 + j] += red[r + off][c * 8 + j];
        }
    }
    __syncthreads();
    if (t < 8) {
        #pragma unroll
        for (int j = 0; j < 8; j++) atomicAdd(&colsum[t * 8 + j], red[0][t * 8 + j]);
    }
}

// ---------------- out = colsum @ w2b + N * b2b ----------------
__global__ void k_final(const float* __restrict__ colsum, const float* __restrict__ w2b,
                        const float* __restrict__ b2b, float* __restrict__ out) {
    int j = threadIdx.x;
    float acc = (float)N_NODES * b2b[j];
    for (int k = 0; k < D; k++) acc += colsum[k] * w2b[k * D + j];
    out[j] = acc;
}

// ---------------- launch ----------------

extern "C" void kernel_launch(void* const* d_in, const int* in_sizes, int n_in,
                              void* d_out, int out_size, void* d_ws, size_t ws_size,
                              hipStream_t stream) {
    const float* x   = (const float*)d_in[0];
    const int*   ei  = (const int*)d_in[1];
    const float* w1a = (const float*)d_in[2];
    const float* b1a = (const float*)d_in[3];
    const float* w1b = (const float*)d_in[4];
    const float* b1b = (const float*)d_in[5];
    const float* w2a = (const float*)d_in[6];
    const float* b2a = (const float*)d_in[7];
    const float* w2b = (const float*)d_in[8];
    const float* b2b = (const float*)d_in[9];
    float* out = (float*)d_out;

    const int* srcp = ei;
    const int* dstp = ei + N_EDGES;

    char* ws = (char*)d_ws;
    unsigned short* z = (unsigned short*)(ws + 0);        // (N+1) rows: 12,800,256 B
    unsigned short* u = (unsigned short*)(ws + 12800256); // 12,800,256 B
    uint2* tmp    = (uint2*)(ws + 25600512);              // 12,800,000 B
    int*   csr    = (int*)(ws + 38400512);                // padded <= 9.2 MB
    int*   bh     = (int*)(ws + 51200512);                // 1,564,000 B
    int*   degarr = (int*)(ws + 52764512);                // 400,000 B
    int*   offs   = (int*)(ws + 53164896);                // 400,064 B
    int*   pb     = (int*)(ws + 53564960);                // 2,048 B
    int*   part   = (int*)(ws + 53567008);                // 2,048 B
    float* colsum = (float*)(ws + 53569056);              // 256 B

    hipMemsetAsync(colsum, 0, D * sizeof(float), stream);
    hipMemsetAsync(z + (size_t)N_NODES * D, 0, D * sizeof(unsigned short), stream);
    hipMemsetAsync(u + (size_t)N_NODES * D, 0, D * sizeof(unsigned short), stream);

    k_hist1   <<<NBLK, 256, 0, stream>>>(dstp, bh);
    k_scanA   <<<SC_NB, 256, 0, stream>>>(bh, part);
    k_scanB   <<<1, 512, 0, stream>>>(part);
    k_scanC   <<<SC_NB, 256, 0, stream>>>(bh, part);
    k_scatter1<<<NBLK, 256, 0, stream>>>(srcp, dstp, bh, tmp);
    k_padsum  <<<NB2, 256, 0, stream>>>(tmp, bh, degarr, pb);
    k_scanP   <<<1, 512, 0, stream>>>(pb);
    k_build2  <<<NB2, 256, 0, stream>>>(tmp, bh, degarr, pb, offs, csr);

    k_gemm1<<<2048, 256, 0, stream>>>(x, w1a, z);
    k_conv1<<<2048, 256, 0, stream>>>(z, offs, csr, b1a, w1b, b1b, w2a, u);
    k_conv2<<<2048, 256, 0, stream>>>(u, offs, csr, b2a, colsum);
    k_final<<<1, 64, 0, stream>>>(colsum, w2b, b2b, out);
}

// Round 9
// 679.824 us; speedup vs baseline: 1.0095x; 1.0095x over previous
//
#include <hip/hip_runtime.h>

#define N_NODES 100000
#define N_EDGES 1600000
#define D_IN 128
#define D 64

#define NBLK 1000          // scatter blocks
#define EPB  1600          // edges per scatter block (NBLK*EPB == N_EDGES)
#define NB2  391           // coarse buckets: dst>>8, max 99999>>8 = 390
#define SC_M  (NB2 * NBLK)                  // 391,000 scan elements
#define SC_CH 1024                          // elements per scan chunk
#define SC_NB ((SC_M + SC_CH - 1) / SC_CH)  // 382 chunks

typedef float vf8 __attribute__((ext_vector_type(8)));

__device__ __forceinline__ float bflo(unsigned int u) {
    union { unsigned int i; float f; } q; q.i = u << 16; return q.f;
}
__device__ __forceinline__ float bfhi(unsigned int u) {
    union { unsigned int i; float f; } q; q.i = u & 0xFFFF0000u; return q.f;
}
__device__ __forceinline__ unsigned short f2bf(float f) {
    unsigned int u = __float_as_uint(f);
    unsigned int r = (u + 0x7FFFu + ((u >> 16) & 1u)) >> 16;   // RNE
    return (unsigned short)r;
}
__device__ __forceinline__ vf8 addrow(vf8 a, uint4 v) {
    a[0] += bflo(v.x); a[1] += bfhi(v.x);
    a[2] += bflo(v.y); a[3] += bfhi(v.y);
    a[4] += bflo(v.z); a[5] += bfhi(v.z);
    a[6] += bflo(v.w); a[7] += bfhi(v.w);
    return a;
}

// padded depth-4 gather, 16 B/lane, all state in named registers
__device__ __forceinline__ vf8 gather4(vf8 acc, const char* __restrict__ zb,
                                       const int* __restrict__ csr,
                                       int e0, int e1, int coff) {
    for (int e = e0; e < e1; e += 4) {
        int4 ia = *(const int4*)(csr + e);
        uint4 v0 = *(const uint4*)(zb + (size_t)ia.x * 128 + coff);
        uint4 v1 = *(const uint4*)(zb + (size_t)ia.y * 128 + coff);
        uint4 v2 = *(const uint4*)(zb + (size_t)ia.z * 128 + coff);
        uint4 v3 = *(const uint4*)(zb + (size_t)ia.w * 128 + coff);
        acc = addrow(acc, v0);
        acc = addrow(acc, v1);
        acc = addrow(acc, v2);
        acc = addrow(acc, v3);
    }
    return acc;
}

// ============ CSR build: two-level counting sort, LDS atomics only ============

__global__ __launch_bounds__(256) void k_hist1(const int* __restrict__ dst,
                                               int* __restrict__ bh) {
    __shared__ int h[NB2];
    int t = threadIdx.x;
    for (int i = t; i < NB2; i += 256) h[i] = 0;
    __syncthreads();
    int base = blockIdx.x * EPB;
    for (int i = t; i < EPB; i += 256) atomicAdd(&h[dst[base + i] >> 8], 1);
    __syncthreads();
    for (int i = t; i < NB2; i += 256) bh[i * NBLK + blockIdx.x] = h[i];
}

__global__ __launch_bounds__(256) void k_scanA(const int* __restrict__ bh,
                                               int* __restrict__ part) {
    __shared__ int s[256];
    int t = threadIdx.x;
    int base = blockIdx.x * SC_CH + t * 4;
    int sum = 0;
    if (base + 3 < SC_M) {
        int4 v = *(const int4*)(bh + base);
        sum = (v.x + v.y) + (v.z + v.w);
    } else {
        for (int k = 0; k < 4; k++) if (base + k < SC_M) sum += bh[base + k];
    }
    s[t] = sum;
    __syncthreads();
    for (int o = 128; o > 0; o >>= 1) {
        if (t < o) s[t] += s[t + o];
        __syncthreads();
    }
    if (t == 0) part[blockIdx.x] = s[0];
}

__global__ __launch_bounds__(512) void k_scanB(int* __restrict__ part) {
    __shared__ int s[512];
    int t = threadIdx.x;
    int v = (t < SC_NB) ? part[t] : 0;
    s[t] = v;
    __syncthreads();
    for (int o = 1; o < 512; o <<= 1) {
        int x = (t >= o) ? s[t - o] : 0;
        __syncthreads();
        s[t] += x;
        __syncthreads();
    }
    if (t < SC_NB) part[t] = s[t] - v;   // exclusive
}

__global__ __launch_bounds__(256) void k_scanC(int* __restrict__ bh,
                                               const int* __restrict__ part) {
    __shared__ int s[256];
    int t = threadIdx.x;
    int base = blockIdx.x * SC_CH + t * 4;
    int4 v = {0, 0, 0, 0};
    if (base + 3 < SC_M) v = *(const int4*)(bh + base);
    else { for (int k = 0; k < 4; k++) if (base + k < SC_M) (&v.x)[k] = bh[base + k]; }
    int sum = (v.x + v.y) + (v.z + v.w);
    s[t] = sum;
    __syncthreads();
    for (int o = 1; o < 256; o <<= 1) {
        int x = (t >= o) ? s[t - o] : 0;
        __syncthreads();
        s[t] += x;
        __syncthreads();
    }
    int run = part[blockIdx.x] + s[t] - sum;
    int4 w;
    w.x = run; run += v.x;
    w.y = run; run += v.y;
    w.z = run; run += v.z;
    w.w = run;
    if (base + 3 < SC_M) *(int4*)(bh + base) = w;
    else { for (int k = 0; k < 4; k++) if (base + k < SC_M) bh[base + k] = (&w.x)[k]; }
}

__global__ __launch_bounds__(256) void k_scatter1(const int* __restrict__ src,
                                                  const int* __restrict__ dst,
                                                  const int* __restrict__ bh,
                                                  uint2* __restrict__ tmp) {
    __shared__ int cur[NB2];
    int t = threadIdx.x;
    for (int i = t; i < NB2; i += 256) cur[i] = bh[i * NBLK + blockIdx.x];
    __syncthreads();
    int base = blockIdx.x * EPB;
    for (int i = t; i < EPB; i += 256) {
        int d = dst[base + i];
        int sv = src[base + i];
        int p = atomicAdd(&cur[d >> 8], 1);
        tmp[p] = make_uint2((unsigned)d, (unsigned)sv);
    }
}

// B1: per-bucket node degrees + padded (multiple-of-4) bucket sums
__global__ __launch_bounds__(256) void k_padsum(const uint2* __restrict__ tmp,
                                                const int* __restrict__ bh,
                                                int* __restrict__ degarr,
                                                int* __restrict__ pb) {
    __shared__ int deg[256];
    __shared__ int s[256];
    int b = blockIdx.x, t = threadIdx.x;
    int e0 = bh[b * NBLK];
    int e1 = (b == NB2 - 1) ? N_EDGES : bh[(b + 1) * NBLK];
    deg[t] = 0;
    __syncthreads();
    for (int i = e0 + t; i < e1; i += 256) atomicAdd(&deg[tmp[i].x & 255u], 1);
    __syncthreads();
    int node = b * 256 + t;
    int d = (node < N_NODES) ? deg[t] : 0;
    if (node < N_NODES) degarr[node] = d;
    int dp = (d + 3) & ~3;
    s[t] = dp;
    __syncthreads();
    for (int o = 128; o > 0; o >>= 1) {
        if (t < o) s[t] += s[t + o];
        __syncthreads();
    }
    if (t == 0) pb[b] = s[0];
}

__global__ __launch_bounds__(512) void k_scanP(int* __restrict__ pb) {
    __shared__ int s[512];
    int t = threadIdx.x;
    int v = (t < NB2) ? pb[t] : 0;
    s[t] = v;
    __syncthreads();
    for (int o = 1; o < 512; o <<= 1) {
        int x = (t >= o) ? s[t - o] : 0;
        __syncthreads();
        s[t] += x;
        __syncthreads();
    }
    if (t < NB2) pb[t] = s[t] - v;   // exclusive
}

// B3: padded CSR build (pad slots -> N_NODES = zero row)
__global__ __launch_bounds__(256) void k_build2(const uint2* __restrict__ tmp,
                                                const int* __restrict__ bh,
                                                const int* __restrict__ degarr,
                                                const int* __restrict__ pb,
                                                int* __restrict__ offs,
                                                int* __restrict__ csr) {
    __shared__ int s[256];
    __shared__ int startp[256];
    __shared__ int cur[256];
    int b = blockIdx.x, t = threadIdx.x;
    int e0 = bh[b * NBLK];
    int e1 = (b == NB2 - 1) ? N_EDGES : bh[(b + 1) * NBLK];
    int node = b * 256 + t;
    int d = (node < N_NODES) ? degarr[node] : 0;
    int dp = (d + 3) & ~3;
    s[t] = dp;
    __syncthreads();
    for (int o = 1; o < 256; o <<= 1) {
        int x = (t >= o) ? s[t - o] : 0;
        __syncthreads();
        s[t] += x;
        __syncthreads();
    }
    int st = pb[b] + s[t] - dp;
    startp[t] = st;
    cur[t] = st;
    if (node < N_NODES) {
        offs[node] = st;
        if (node == N_NODES - 1) offs[N_NODES] = st + dp;
    }
    __syncthreads();
    for (int i = e0 + t; i < e1; i += 256) {
        uint2 p = tmp[i];
        int pos = atomicAdd(&cur[p.x & 255u], 1);
        csr[pos] = (int)p.y;
    }
    __syncthreads();
    int end = startp[t] + dp;
    for (int p = cur[t]; p < end; p++) csr[p] = N_NODES;   // zero-row index
}

// ---------------- z = x @ w1a  (128 -> 64, no bias), z stored bf16 ----------------
__global__ __launch_bounds__(256) void k_gemm1(const float* __restrict__ x,
                                               const float* __restrict__ w,
                                               unsigned short* __restrict__ z) {
    __shared__ float ws[D_IN][D];        // 32 KB
    __shared__ float xs[16][D_IN + 1];
    int t = threadIdx.x;
    {
        const float4* w4 = (const float4*)w;
        float4* s4 = (float4*)&ws[0][0];
        for (int i = t; i < (D_IN * D) / 4; i += 256) s4[i] = w4[i];
    }
    int r = t >> 4, c = t & 15;
    __syncthreads();
    for (int base = blockIdx.x * 16; base < N_NODES; base += gridDim.x * 16) {
        for (int i = t; i < 16 * (D_IN / 4); i += 256) {
            int row = i >> 5, k4 = i & 31;
            float4 v = ((const float4*)(x + (size_t)(base + row) * D_IN))[k4];
            xs[row][k4 * 4 + 0] = v.x; xs[row][k4 * 4 + 1] = v.y;
            xs[row][k4 * 4 + 2] = v.z; xs[row][k4 * 4 + 3] = v.w;
        }
        __syncthreads();
        float4 acc = {0.f, 0.f, 0.f, 0.f};
        for (int k = 0; k < D_IN; k++) {
            float xv = xs[r][k];
            float4 wv = *(const float4*)&ws[k][c * 4];
            acc.x += xv * wv.x; acc.y += xv * wv.y;
            acc.z += xv * wv.z; acc.w += xv * wv.w;
        }
        ushort4 p;
        p.x = f2bf(acc.x); p.y = f2bf(acc.y); p.z = f2bf(acc.z); p.w = f2bf(acc.w);
        *(ushort4*)(z + (size_t)(base + r) * D + c * 4) = p;
        __syncthreads();
    }
}

// ---------------- conv1 fused: agg(z)+b1a+relu, @w1b+b1b relu, @w2a -> u (bf16) ----------------
// 8 lanes/node, 32 nodes/block. LDS: 16 KB weights + 2*8.7 KB h -> 4 blocks/CU.
#define HS 68   // h row stride (floats)
__global__ __launch_bounds__(256, 4) void k_conv1(const unsigned short* __restrict__ z,
                                                  const int* __restrict__ offs,
                                                  const int* __restrict__ csr,
                                                  const float* __restrict__ b1a,
                                                  const float* __restrict__ w1b,
                                                  const float* __restrict__ b1b,
                                                  const float* __restrict__ w2a,
                                                  unsigned short* __restrict__ u) {
    __shared__ unsigned short w1s[D][D];   // 8 KB bf16
    __shared__ unsigned short w2s[D][D];   // 8 KB bf16
    __shared__ float h1s[32][HS];
    __shared__ float h2s[32][HS];
    int t = threadIdx.x;
    int r = t >> 3, c = t & 7;
    {
        for (int i = t; i < (D * D) / 4; i += 256) {
            float4 a = ((const float4*)w1b)[i];
            ushort4 p; p.x = f2bf(a.x); p.y = f2bf(a.y); p.z = f2bf(a.z); p.w = f2bf(a.w);
            *(ushort4*)&(&w1s[0][0])[i * 4] = p;
            float4 b = ((const float4*)w2a)[i];
            ushort4 q; q.x = f2bf(b.x); q.y = f2bf(b.y); q.z = f2bf(b.z); q.w = f2bf(b.w);
            *(ushort4*)&(&w2s[0][0])[i * 4] = q;
        }
    }
    vf8 vb1a, vb1b;
    {
        float4 a0 = ((const float4*)b1a)[c * 2], a1 = ((const float4*)b1a)[c * 2 + 1];
        vb1a[0] = a0.x; vb1a[1] = a0.y; vb1a[2] = a0.z; vb1a[3] = a0.w;
        vb1a[4] = a1.x; vb1a[5] = a1.y; vb1a[6] = a1.z; vb1a[7] = a1.w;
        float4 b0 = ((const float4*)b1b)[c * 2], b1 = ((const float4*)b1b)[c * 2 + 1];
        vb1b[0] = b0.x; vb1b[1] = b0.y; vb1b[2] = b0.z; vb1b[3] = b0.w;
        vb1b[4] = b1.x; vb1b[5] = b1.y; vb1b[6] = b1.z; vb1b[7] = b1.w;
    }
    __syncthreads();

    const char* zb = (const char*)z;
    const int coff = c * 16;
    for (int base = blockIdx.x * 32; base < N_NODES; base += gridDim.x * 32) {
        int node = base + r;   // N_NODES % 32 == 0
        vf8 acc = vb1a;
        acc = addrow(acc, *(const uint4*)(zb + (size_t)node * 128 + coff));
        int e0 = offs[node], e1 = offs[node + 1];
        acc = gather4(acc, zb, csr, e0, e1, coff);
        *(float4*)&h1s[r][c * 8]     = make_float4(fmaxf(acc[0], 0.f), fmaxf(acc[1], 0.f),
                                                   fmaxf(acc[2], 0.f), fmaxf(acc[3], 0.f));
        *(float4*)&h1s[r][c * 8 + 4] = make_float4(fmaxf(acc[4], 0.f), fmaxf(acc[5], 0.f),
                                                   fmaxf(acc[6], 0.f), fmaxf(acc[7], 0.f));
        __syncthreads();
        // --- h2 = relu(h1 @ w1b + b1b) ---
        vf8 a2 = vb1b;
        for (int k = 0; k < D; k++) {
            float hv = h1s[r][k];
            uint4 w = *(const uint4*)&w1s[k][c * 8];
            a2[0] += hv * bflo(w.x); a2[1] += hv * bfhi(w.x);
            a2[2] += hv * bflo(w.y); a2[3] += hv * bfhi(w.y);
            a2[4] += hv * bflo(w.z); a2[5] += hv * bfhi(w.z);
            a2[6] += hv * bflo(w.w); a2[7] += hv * bfhi(w.w);
        }
        *(float4*)&h2s[r][c * 8]     = make_float4(fmaxf(a2[0], 0.f), fmaxf(a2[1], 0.f),
                                                   fmaxf(a2[2], 0.f), fmaxf(a2[3], 0.f));
        *(float4*)&h2s[r][c * 8 + 4] = make_float4(fmaxf(a2[4], 0.f), fmaxf(a2[5], 0.f),
                                                   fmaxf(a2[6], 0.f), fmaxf(a2[7], 0.f));
        __syncthreads();
        // --- u = h2 @ w2a  (bias b2a applied in conv2 agg), u stored bf16 ---
        vf8 a3 = 0.f;
        for (int k = 0; k < D; k++) {
            float hv = h2s[r][k];
            uint4 w = *(const uint4*)&w2s[k][c * 8];
            a3[0] += hv * bflo(w.x); a3[1] += hv * bfhi(w.x);
            a3[2] += hv * bflo(w.y); a3[3] += hv * bfhi(w.y);
            a3[4] += hv * bflo(w.z); a3[5] += hv * bfhi(w.z);
            a3[6] += hv * bflo(w.w); a3[7] += hv * bfhi(w.w);
        }
        uint4 p;
        p.x = ((unsigned)f2bf(a3[1]) << 16) | f2bf(a3[0]);
        p.y = ((unsigned)f2bf(a3[3]) << 16) | f2bf(a3[2]);
        p.z = ((unsigned)f2bf(a3[5]) << 16) | f2bf(a3[4]);
        p.w = ((unsigned)f2bf(a3[7]) << 16) | f2bf(a3[6]);
        *(uint4*)((char*)u + (size_t)node * 128 + coff) = p;
        __syncthreads();
    }
}

// ---------------- conv2 fused: agg(u) + b2a + relu -> column sum ----------------
__global__ __launch_bounds__(256) void k_conv2(const unsigned short* __restrict__ u,
                                               const int* __restrict__ offs,
                                               const int* __restrict__ csr,
                                               const float* __restrict__ b2a,
                                               float* __restrict__ colsum) {
    __shared__ float red[32][HS];
    int t = threadIdx.x;
    int r = t >> 3, c = t & 7;
    vf8 vb;
    {
        float4 a0 = ((const float4*)b2a)[c * 2], a1 = ((const float4*)b2a)[c * 2 + 1];
        vb[0] = a0.x; vb[1] = a0.y; vb[2] = a0.z; vb[3] = a0.w;
        vb[4] = a1.x; vb[5] = a1.y; vb[6] = a1.z; vb[7] = a1.w;
    }
    vf8 cs = 0.f;
    const char* ub = (const char*)u;
    const int coff = c * 16;
    for (int base = blockIdx.x * 32; base < N_NODES; base += gridDim.x * 32) {
        int node = base + r;
        vf8 acc = vb;
        acc = addrow(acc, *(const uint4*)(ub + (size_t)node * 128 + coff));
        int e0 = offs[node], e1 = offs[node + 1];
        acc = gather4(acc, ub, csr, e0, e1, coff);
        cs[0] += fmaxf(acc[0], 0.f); cs[1] += fmaxf(acc[1], 0.f);
        cs[2] += fmaxf(acc[2], 0.f); cs[3] += fmaxf(acc[3], 0.f);
        cs[4] += fmaxf(acc[4], 0.f); cs[5] += fmaxf(acc[5], 0.f);
        cs[6] += fmaxf(acc[6], 0.f); cs[7] += fmaxf(acc[7], 0.f);
    }
    *(float4*)&red[r][c * 8]     = make_float4(cs[0], cs[1], cs[2], cs[3]);
    *(float4*)&red[r][c * 8 + 4] = make_float4(cs[4], cs[5], cs[6], cs[7]);
    for (int off = 16; off >= 1; off >>= 1) {
        __syncthreads();
        if (r < off) {
            #pragma unroll
            for (int j = 0; j < 8; j++) red[r][c * 8 + j] += red[r + off][c * 8 + j];
        }
    }
    __syncthreads();
    if (t < 8) {
        #pragma unroll
        for (int j = 0; j < 8; j++) atomicAdd(&colsum[t * 8 + j], red[0][t * 8 + j]);
    }
}

// ---------------- out = colsum @ w2b + N * b2b ----------------
__global__ void k_final(const float* __restrict__ colsum, const float* __restrict__ w2b,
                        const float* __restrict__ b2b, float* __restrict__ out) {
    int j = threadIdx.x;
    float acc = (float)N_NODES * b2b[j];
    for (int k = 0; k < D; k++) acc += colsum[k] * w2b[k * D + j];
    out[j] = acc;
}

// ---------------- launch ----------------

extern "C" void kernel_launch(void* const* d_in, const int* in_sizes, int n_in,
                              void* d_out, int out_size, void* d_ws, size_t ws_size,
                              hipStream_t stream) {
    const float* x   = (const float*)d_in[0];
    const int*   ei  = (const int*)d_in[1];
    const float* w1a = (const float*)d_in[2];
    const float* b1a = (const float*)d_in[3];
    const float* w1b = (const float*)d_in[4];
    const float* b1b = (const float*)d_in[5];
    const float* w2a = (const float*)d_in[6];
    const float* b2a = (const float*)d_in[7];
    const float* w2b = (const float*)d_in[8];
    const float* b2b = (const float*)d_in[9];
    float* out = (float*)d_out;

    const int* srcp = ei;
    const int* dstp = ei + N_EDGES;

    char* ws = (char*)d_ws;
    unsigned short* z = (unsigned short*)(ws + 0);        // (N+1) rows: 12,800,256 B
    unsigned short* u = (unsigned short*)(ws + 12800256); // 12,800,256 B
    uint2* tmp    = (uint2*)(ws + 25600512);              // 12,800,000 B
    int*   csr    = (int*)(ws + 38400512);                // padded <= 7.7 MB
    int*   bh     = (int*)(ws + 51200512);                // 1,564,000 B
    int*   degarr = (int*)(ws + 52764512);                // 400,000 B
    int*   offs   = (int*)(ws + 53164896);                // 400,064 B
    int*   pb     = (int*)(ws + 53564960);                // 2,048 B
    int*   part   = (int*)(ws + 53567008);                // 2,048 B
    float* colsum = (float*)(ws + 53569056);              // 256 B

    hipMemsetAsync(colsum, 0, D * sizeof(float), stream);
    hipMemsetAsync(z + (size_t)N_NODES * D, 0, D * sizeof(unsigned short), stream);
    hipMemsetAsync(u + (size_t)N_NODES * D, 0, D * sizeof(unsigned short), stream);

    k_hist1   <<<NBLK, 256, 0, stream>>>(dstp, bh);
    k_scanA   <<<SC_NB, 256, 0, stream>>>(bh, part);
    k_scanB   <<<1, 512, 0, stream>>>(part);
    k_scanC   <<<SC_NB, 256, 0, stream>>>(bh, part);
    k_scatter1<<<NBLK, 256, 0, stream>>>(srcp, dstp, bh, tmp);
    k_padsum  <<<NB2, 256, 0, stream>>>(tmp, bh, degarr, pb);
    k_scanP   <<<1, 512, 0, stream>>>(pb);
    k_build2  <<<NB2, 256, 0, stream>>>(tmp, bh, degarr, pb, offs, csr);

    k_gemm1<<<2048, 256, 0, stream>>>(x, w1a, z);
    k_conv1<<<2048, 256, 0, stream>>>(z, offs, csr, b1a, w1b, b1b, w2a, u);
    k_conv2<<<2048, 256, 0, stream>>>(u, offs, csr, b2a, colsum);
    k_final<<<1, 64, 0, stream>>>(colsum, w2b, b2b, out);
}

// Round 10
// 493.178 us; speedup vs baseline: 1.3916x; 1.3785x over previous
//
#include <hip/hip_runtime.h>

#define N_NODES 100000
#define N_EDGES 1600000
#define D_IN 128
#define D 64

#define NBLK 1000          // scatter blocks
#define EPB  1600          // edges per scatter block (NBLK*EPB == N_EDGES)
#define NB2  391           // coarse buckets: dst>>8, max 99999>>8 = 390
#define SC_M  (NB2 * NBLK)                  // 391,000 scan elements
#define SC_CH 1024                          // elements per scan chunk
#define SC_NB ((SC_M + SC_CH - 1) / SC_CH)  // 382 chunks

__device__ __forceinline__ float bf2f(unsigned short u) {
    union { unsigned int i; float f; } q; q.i = ((unsigned int)u) << 16; return q.f;
}
__device__ __forceinline__ unsigned short f2bf(float f) {
    unsigned int u = __float_as_uint(f);
    unsigned int r = (u + 0x7FFFu + ((u >> 16) & 1u)) >> 16;   // RNE
    return (unsigned short)r;
}
__device__ __forceinline__ void acc4(float4& a, ushort4 v) {
    a.x += bf2f(v.x); a.y += bf2f(v.y); a.z += bf2f(v.z); a.w += bf2f(v.w);
}

// ============ CSR build: two-level counting sort, LDS atomics only ============

__global__ __launch_bounds__(256) void k_hist1(const int* __restrict__ dst,
                                               int* __restrict__ bh) {
    __shared__ int h[NB2];
    int t = threadIdx.x;
    for (int i = t; i < NB2; i += 256) h[i] = 0;
    __syncthreads();
    int base = blockIdx.x * EPB;
    for (int i = t; i < EPB; i += 256) atomicAdd(&h[dst[base + i] >> 8], 1);
    __syncthreads();
    for (int i = t; i < NB2; i += 256) bh[i * NBLK + blockIdx.x] = h[i];
}

__global__ __launch_bounds__(256) void k_scanA(const int* __restrict__ bh,
                                               int* __restrict__ part) {
    __shared__ int s[256];
    int t = threadIdx.x;
    int base = blockIdx.x * SC_CH + t * 4;
    int sum = 0;
    if (base + 3 < SC_M) {
        int4 v = *(const int4*)(bh + base);
        sum = (v.x + v.y) + (v.z + v.w);
    } else {
        for (int k = 0; k < 4; k++) if (base + k < SC_M) sum += bh[base + k];
    }
    s[t] = sum;
    __syncthreads();
    for (int o = 128; o > 0; o >>= 1) {
        if (t < o) s[t] += s[t + o];
        __syncthreads();
    }
    if (t == 0) part[blockIdx.x] = s[0];
}

__global__ __launch_bounds__(512) void k_scanB(int* __restrict__ part) {
    __shared__ int s[512];
    int t = threadIdx.x;
    int v = (t < SC_NB) ? part[t] : 0;
    s[t] = v;
    __syncthreads();
    for (int o = 1; o < 512; o <<= 1) {
        int x = (t >= o) ? s[t - o] : 0;
        __syncthreads();
        s[t] += x;
        __syncthreads();
    }
    if (t < SC_NB) part[t] = s[t] - v;   // exclusive
}

__global__ __launch_bounds__(256) void k_scanC(int* __restrict__ bh,
                                               const int* __restrict__ part) {
    __shared__ int s[256];
    int t = threadIdx.x;
    int base = blockIdx.x * SC_CH + t * 4;
    int4 v = {0, 0, 0, 0};
    if (base + 3 < SC_M) v = *(const int4*)(bh + base);
    else { for (int k = 0; k < 4; k++) if (base + k < SC_M) (&v.x)[k] = bh[base + k]; }
    int sum = (v.x + v.y) + (v.z + v.w);
    s[t] = sum;
    __syncthreads();
    for (int o = 1; o < 256; o <<= 1) {
        int x = (t >= o) ? s[t - o] : 0;
        __syncthreads();
        s[t] += x;
        __syncthreads();
    }
    int run = part[blockIdx.x] + s[t] - sum;
    int4 w;
    w.x = run; run += v.x;
    w.y = run; run += v.y;
    w.z = run; run += v.z;
    w.w = run;
    if (base + 3 < SC_M) *(int4*)(bh + base) = w;
    else { for (int k = 0; k < 4; k++) if (base + k < SC_M) bh[base + k] = (&w.x)[k]; }
}

__global__ __launch_bounds__(256) void k_scatter1(const int* __restrict__ src,
                                                  const int* __restrict__ dst,
                                                  const int* __restrict__ bh,
                                                  uint2* __restrict__ tmp) {
    __shared__ int cur[NB2];
    int t = threadIdx.x;
    for (int i = t; i < NB2; i += 256) cur[i] = bh[i * NBLK + blockIdx.x];
    __syncthreads();
    int base = blockIdx.x * EPB;
    for (int i = t; i < EPB; i += 256) {
        int d = dst[base + i];
        int sv = src[base + i];
        int p = atomicAdd(&cur[d >> 8], 1);
        tmp[p] = make_uint2((unsigned)d, (unsigned)sv);
    }
}

// B: per-bucket fine sort -> offs + csr (256 nodes/bucket, all in LDS), unpadded
__global__ __launch_bounds__(256) void k_build(const uint2* __restrict__ tmp,
                                               const int* __restrict__ bh,
                                               int* __restrict__ offs,
                                               int* __restrict__ csr) {
    __shared__ int deg[256];
    __shared__ int s[256];
    __shared__ int cur[256];
    int b = blockIdx.x;
    int t = threadIdx.x;
    int e0 = bh[b * NBLK];
    int e1 = (b == NB2 - 1) ? N_EDGES : bh[(b + 1) * NBLK];
    deg[t] = 0;
    __syncthreads();
    for (int i = e0 + t; i < e1; i += 256) atomicAdd(&deg[tmp[i].x & 255u], 1);
    __syncthreads();
    int v = deg[t];
    s[t] = v;
    __syncthreads();
    for (int o = 1; o < 256; o <<= 1) {
        int x = (t >= o) ? s[t - o] : 0;
        __syncthreads();
        s[t] += x;
        __syncthreads();
    }
    int start = e0 + s[t] - v;      // exclusive
    int node = b * 256 + t;
    if (node < N_NODES) offs[node] = start;
    cur[t] = start;
    __syncthreads();
    for (int i = e0 + t; i < e1; i += 256) {
        uint2 p = tmp[i];
        int pos = atomicAdd(&cur[p.x & 255u], 1);
        csr[pos] = (int)p.y;
    }
    if (b == 0 && t == 0) offs[N_NODES] = N_EDGES;
}

// ---------------- z = x @ w1a  (128 -> 64, no bias), z stored bf16 ----------------
__global__ __launch_bounds__(256) void k_gemm1(const float* __restrict__ x,
                                               const float* __restrict__ w,
                                               unsigned short* __restrict__ z) {
    __shared__ float ws[D_IN][D];        // 32 KB
    __shared__ float xs[16][D_IN + 1];
    int t = threadIdx.x;
    {
        const float4* w4 = (const float4*)w;
        float4* s4 = (float4*)&ws[0][0];
        for (int i = t; i < (D_IN * D) / 4; i += 256) s4[i] = w4[i];
    }
    int r = t >> 4, c = t & 15;
    __syncthreads();
    for (int base = blockIdx.x * 16; base < N_NODES; base += gridDim.x * 16) {
        for (int i = t; i < 16 * (D_IN / 4); i += 256) {
            int row = i >> 5, k4 = i & 31;
            float4 v = ((const float4*)(x + (size_t)(base + row) * D_IN))[k4];
            xs[row][k4 * 4 + 0] = v.x; xs[row][k4 * 4 + 1] = v.y;
            xs[row][k4 * 4 + 2] = v.z; xs[row][k4 * 4 + 3] = v.w;
        }
        __syncthreads();
        float4 acc = {0.f, 0.f, 0.f, 0.f};
        for (int k = 0; k < D_IN; k++) {
            float xv = xs[r][k];
            float4 wv = *(const float4*)&ws[k][c * 4];
            acc.x += xv * wv.x; acc.y += xv * wv.y;
            acc.z += xv * wv.z; acc.w += xv * wv.w;
        }
        ushort4 p;
        p.x = f2bf(acc.x); p.y = f2bf(acc.y); p.z = f2bf(acc.z); p.w = f2bf(acc.w);
        *(ushort4*)(z + (size_t)(base + r) * D + c * 4) = p;
        __syncthreads();
    }
}

// ---------------- conv1 fused: agg(z)+b1a+relu, @w1b+b1b relu, @w2a -> u (bf16) ----------------
__global__ __launch_bounds__(256, 6) void k_conv1(const unsigned short* __restrict__ z,
                                                  const int* __restrict__ offs,
                                                  const int* __restrict__ csr,
                                                  const float* __restrict__ b1a,
                                                  const float* __restrict__ w1b,
                                                  const float* __restrict__ b1b,
                                                  const float* __restrict__ w2a,
                                                  unsigned short* __restrict__ u) {
    __shared__ unsigned short w1s[D][D];   // 8 KB bf16
    __shared__ unsigned short w2s[D][D];   // 8 KB bf16
    __shared__ float h1s[16][D + 1];
    __shared__ float h2s[16][D + 1];
    int t = threadIdx.x;
    int r = t >> 4, c = t & 15;
    {
        for (int i = t; i < (D * D) / 4; i += 256) {
            float4 a = ((const float4*)w1b)[i];
            ushort4 p; p.x = f2bf(a.x); p.y = f2bf(a.y); p.z = f2bf(a.z); p.w = f2bf(a.w);
            *(ushort4*)&(&w1s[0][0])[i * 4] = p;
            float4 b = ((const float4*)w2a)[i];
            ushort4 q; q.x = f2bf(b.x); q.y = f2bf(b.y); q.z = f2bf(b.z); q.w = f2bf(b.w);
            *(ushort4*)&(&w2s[0][0])[i * 4] = q;
        }
    }
    float4 vb1a = ((const float4*)b1a)[c];
    float4 vb1b = ((const float4*)b1b)[c];
    __syncthreads();

    const size_t c4 = (size_t)(c * 4);
    for (int base = blockIdx.x * 16; base < N_NODES; base += gridDim.x * 16) {
        int node = base + r;   // N_NODES % 16 == 0
        // --- aggregate in 64-dim bf16 space, 8-deep load pipeline ---
        float4 acc = {vb1a.x, vb1a.y, vb1a.z, vb1a.w};
        acc4(acc, *(const ushort4*)(z + (size_t)node * D + c4));
        int e0 = offs[node], e1 = offs[node + 1];
        int e = e0;
        for (; e + 8 <= e1; e += 8) {
            int s0 = csr[e + 0], s1 = csr[e + 1], s2 = csr[e + 2], s3 = csr[e + 3];
            int s4 = csr[e + 4], s5 = csr[e + 5], s6 = csr[e + 6], s7 = csr[e + 7];
            ushort4 v0 = *(const ushort4*)(z + (size_t)s0 * D + c4);
            ushort4 v1 = *(const ushort4*)(z + (size_t)s1 * D + c4);
            ushort4 v2 = *(const ushort4*)(z + (size_t)s2 * D + c4);
            ushort4 v3 = *(const ushort4*)(z + (size_t)s3 * D + c4);
            ushort4 v4 = *(const ushort4*)(z + (size_t)s4 * D + c4);
            ushort4 v5 = *(const ushort4*)(z + (size_t)s5 * D + c4);
            ushort4 v6 = *(const ushort4*)(z + (size_t)s6 * D + c4);
            ushort4 v7 = *(const ushort4*)(z + (size_t)s7 * D + c4);
            acc4(acc, v0); acc4(acc, v1); acc4(acc, v2); acc4(acc, v3);
            acc4(acc, v4); acc4(acc, v5); acc4(acc, v6); acc4(acc, v7);
        }
        for (; e < e1; e++) {
            int s = csr[e];
            acc4(acc, *(const ushort4*)(z + (size_t)s * D + c4));
        }
        h1s[r][c * 4 + 0] = fmaxf(acc.x, 0.f);
        h1s[r][c * 4 + 1] = fmaxf(acc.y, 0.f);
        h1s[r][c * 4 + 2] = fmaxf(acc.z, 0.f);
        h1s[r][c * 4 + 3] = fmaxf(acc.w, 0.f);
        __syncthreads();
        // --- h2 = relu(h1 @ w1b + b1b) ---
        float4 a2 = vb1b;
        for (int k = 0; k < D; k++) {
            float hv = h1s[r][k];
            ushort4 wv = *(const ushort4*)&w1s[k][c * 4];
            a2.x += hv * bf2f(wv.x); a2.y += hv * bf2f(wv.y);
            a2.z += hv * bf2f(wv.z); a2.w += hv * bf2f(wv.w);
        }
        h2s[r][c * 4 + 0] = fmaxf(a2.x, 0.f);
        h2s[r][c * 4 + 1] = fmaxf(a2.y, 0.f);
        h2s[r][c * 4 + 2] = fmaxf(a2.z, 0.f);
        h2s[r][c * 4 + 3] = fmaxf(a2.w, 0.f);
        __syncthreads();
        // --- u = h2 @ w2a  (bias b2a applied in conv2 agg), u stored bf16 ---
        float4 a3 = {0.f, 0.f, 0.f, 0.f};
        for (int k = 0; k < D; k++) {
            float hv = h2s[r][k];
            ushort4 wv = *(const ushort4*)&w2s[k][c * 4];
            a3.x += hv * bf2f(wv.x); a3.y += hv * bf2f(wv.y);
            a3.z += hv * bf2f(wv.z); a3.w += hv * bf2f(wv.w);
        }
        ushort4 p;
        p.x = f2bf(a3.x); p.y = f2bf(a3.y); p.z = f2bf(a3.z); p.w = f2bf(a3.w);
        *(ushort4*)(u + (size_t)node * D + c4) = p;
        __syncthreads();
    }
}

// ---------------- conv2 fused: agg(u) + b2a + relu -> column sum ----------------
__global__ __launch_bounds__(256) void k_conv2(const unsigned short* __restrict__ u,
                                               const int* __restrict__ offs,
                                               const int* __restrict__ csr,
                                               const float* __restrict__ b2a,
                                               float* __restrict__ colsum) {
    __shared__ float red[16][D + 1];
    int t = threadIdx.x;
    int r = t >> 4, c = t & 15;
    float4 vb = ((const float4*)b2a)[c];
    float4 cs = {0.f, 0.f, 0.f, 0.f};
    const size_t c4 = (size_t)(c * 4);
    for (int base = blockIdx.x * 16; base < N_NODES; base += gridDim.x * 16) {
        int node = base + r;
        float4 acc = {vb.x, vb.y, vb.z, vb.w};
        acc4(acc, *(const ushort4*)(u + (size_t)node * D + c4));
        int e0 = offs[node], e1 = offs[node + 1];
        int e = e0;
        for (; e + 8 <= e1; e += 8) {
            int s0 = csr[e + 0], s1 = csr[e + 1], s2 = csr[e + 2], s3 = csr[e + 3];
            int s4 = csr[e + 4], s5 = csr[e + 5], s6 = csr[e + 6], s7 = csr[e + 7];
            ushort4 v0 = *(const ushort4*)(u + (size_t)s0 * D + c4);
            ushort4 v1 = *(const ushort4*)(u + (size_t)s1 * D + c4);
            ushort4 v2 = *(const ushort4*)(u + (size_t)s2 * D + c4);
            ushort4 v3 = *(const ushort4*)(u + (size_t)s3 * D + c4);
            ushort4 v4 = *(const ushort4*)(u + (size_t)s4 * D + c4);
            ushort4 v5 = *(const ushort4*)(u + (size_t)s5 * D + c4);
            ushort4 v6 = *(const ushort4*)(u + (size_t)s6 * D + c4);
            ushort4 v7 = *(const ushort4*)(u + (size_t)s7 * D + c4);
            acc4(acc, v0); acc4(acc, v1); acc4(acc, v2); acc4(acc, v3);
            acc4(acc, v4); acc4(acc, v5); acc4(acc, v6); acc4(acc, v7);
        }
        for (; e < e1; e++) {
            int s = csr[e];
            acc4(acc, *(const ushort4*)(u + (size_t)s * D + c4));
        }
        cs.x += fmaxf(acc.x, 0.f); cs.y += fmaxf(acc.y, 0.f);
        cs.z += fmaxf(acc.z, 0.f); cs.w += fmaxf(acc.w, 0.f);
    }
    red[r][c * 4 + 0] = cs.x; red[r][c * 4 + 1] = cs.y;
    red[r][c * 4 + 2] = cs.z; red[r][c * 4 + 3] = cs.w;
    __syncthreads();
    if (r == 0) {
        float4 tot = {0.f, 0.f, 0.f, 0.f};
        for (int rr = 0; rr < 16; rr++) {
            tot.x += red[rr][c * 4 + 0]; tot.y += red[rr][c * 4 + 1];
            tot.z += red[rr][c * 4 + 2]; tot.w += red[rr][c * 4 + 3];
        }
        atomicAdd(&colsum[c * 4 + 0], tot.x);
        atomicAdd(&colsum[c * 4 + 1], tot.y);
        atomicAdd(&colsum[c * 4 + 2], tot.z);
        atomicAdd(&colsum[c * 4 + 3], tot.w);
    }
}

// ---------------- out = colsum @ w2b + N * b2b ----------------
__global__ void k_final(const float* __restrict__ colsum, const float* __restrict__ w2b,
                        const float* __restrict__ b2b, float* __restrict__ out) {
    int j = threadIdx.x;
    float acc = (float)N_NODES * b2b[j];
    for (int k = 0; k < D; k++) acc += colsum[k] * w2b[k * D + j];
    out[j] = acc;
}

// ---------------- launch ----------------

extern "C" void kernel_launch(void* const* d_in, const int* in_sizes, int n_in,
                              void* d_out, int out_size, void* d_ws, size_t ws_size,
                              hipStream_t stream) {
    const float* x   = (const float*)d_in[0];
    const int*   ei  = (const int*)d_in[1];
    const float* w1a = (const float*)d_in[2];
    const float* b1a = (const float*)d_in[3];
    const float* w1b = (const float*)d_in[4];
    const float* b1b = (const float*)d_in[5];
    const float* w2a = (const float*)d_in[6];
    const float* b2a = (const float*)d_in[7];
    const float* w2b = (const float*)d_in[8];
    const float* b2b = (const float*)d_in[9];
    float* out = (float*)d_out;

    const int* srcp = ei;
    const int* dstp = ei + N_EDGES;

    char* ws = (char*)d_ws;
    unsigned short* z = (unsigned short*)(ws + 0);        // 12,800,000 B
    unsigned short* u = (unsigned short*)(ws + 12800000); // 12,800,000 B
    uint2* tmp    = (uint2*)(ws + 25600000);              // 12,800,000 B
    int*   csr    = (int*)(ws + 38400000);                // 6,400,000 B
    int*   bh     = (int*)(ws + 44800000);                // 1,564,000 B
    int*   offs   = (int*)(ws + 46364000);                // 400,004 B -> pad
    int*   part   = (int*)(ws + 46764032);                // 2,048 B
    float* colsum = (float*)(ws + 46766080);              // 256 B

    hipMemsetAsync(colsum, 0, D * sizeof(float), stream);

    k_hist1   <<<NBLK, 256, 0, stream>>>(dstp, bh);
    k_scanA   <<<SC_NB, 256, 0, stream>>>(bh, part);
    k_scanB   <<<1, 512, 0, stream>>>(part);
    k_scanC   <<<SC_NB, 256, 0, stream>>>(bh, part);
    k_scatter1<<<NBLK, 256, 0, stream>>>(srcp, dstp, bh, tmp);
    k_build   <<<NB2, 256, 0, stream>>>(tmp, bh, offs, csr);

    k_gemm1<<<2048, 256, 0, stream>>>(x, w1a, z);
    k_conv1<<<2048, 256, 0, stream>>>(z, offs, csr, b1a, w1b, b1b, w2a, u);
    k_conv2<<<2048, 256, 0, stream>>>(u, offs, csr, b2a, colsum);
    k_final<<<1, 64, 0, stream>>>(colsum, w2b, b2b, out);
}

// Round 11
// 486.416 us; speedup vs baseline: 1.4109x; 1.0139x over previous
//
#include <hip/hip_runtime.h>

#define N_NODES 100000
#define N_EDGES 1600000
#define D_IN 128
#define D 64

#define NBLK 1000          // scatter blocks
#define EPB  1600          // edges per scatter block (NBLK*EPB == N_EDGES)
#define NB2  391           // coarse buckets: dst>>8, max 99999>>8 = 390
#define SC_M  (NB2 * NBLK)                  // 391,000 scan elements
#define SC_CH 1024                          // elements per scan chunk
#define SC_NB ((SC_M + SC_CH - 1) / SC_CH)  // 382 chunks

__device__ __forceinline__ float bf2f(unsigned short u) {
    union { unsigned int i; float f; } q; q.i = ((unsigned int)u) << 16; return q.f;
}
__device__ __forceinline__ unsigned short f2bf(float f) {
    unsigned int u = __float_as_uint(f);
    unsigned int r = (u + 0x7FFFu + ((u >> 16) & 1u)) >> 16;   // RNE
    return (unsigned short)r;
}
__device__ __forceinline__ void acc4(float4& a, ushort4 v) {
    a.x += bf2f(v.x); a.y += bf2f(v.y); a.z += bf2f(v.z); a.w += bf2f(v.w);
}

// ============ CSR build: two-level counting sort, LDS atomics only ============

__global__ __launch_bounds__(256) void k_hist1(const int* __restrict__ dst,
                                               int* __restrict__ bh) {
    __shared__ int h[NB2];
    int t = threadIdx.x;
    for (int i = t; i < NB2; i += 256) h[i] = 0;
    __syncthreads();
    int base = blockIdx.x * EPB;
    for (int i = t; i < EPB; i += 256) atomicAdd(&h[dst[base + i] >> 8], 1);
    __syncthreads();
    for (int i = t; i < NB2; i += 256) bh[i * NBLK + blockIdx.x] = h[i];
}

__global__ __launch_bounds__(256) void k_scanA(const int* __restrict__ bh,
                                               int* __restrict__ part) {
    __shared__ int s[256];
    int t = threadIdx.x;
    int base = blockIdx.x * SC_CH + t * 4;
    int sum = 0;
    if (base + 3 < SC_M) {
        int4 v = *(const int4*)(bh + base);
        sum = (v.x + v.y) + (v.z + v.w);
    } else {
        for (int k = 0; k < 4; k++) if (base + k < SC_M) sum += bh[base + k];
    }
    s[t] = sum;
    __syncthreads();
    for (int o = 128; o > 0; o >>= 1) {
        if (t < o) s[t] += s[t + o];
        __syncthreads();
    }
    if (t == 0) part[blockIdx.x] = s[0];
}

__global__ __launch_bounds__(512) void k_scanB(int* __restrict__ part) {
    __shared__ int s[512];
    int t = threadIdx.x;
    int v = (t < SC_NB) ? part[t] : 0;
    s[t] = v;
    __syncthreads();
    for (int o = 1; o < 512; o <<= 1) {
        int x = (t >= o) ? s[t - o] : 0;
        __syncthreads();
        s[t] += x;
        __syncthreads();
    }
    if (t < SC_NB) part[t] = s[t] - v;   // exclusive
}

__global__ __launch_bounds__(256) void k_scanC(int* __restrict__ bh,
                                               const int* __restrict__ part) {
    __shared__ int s[256];
    int t = threadIdx.x;
    int base = blockIdx.x * SC_CH + t * 4;
    int4 v = {0, 0, 0, 0};
    if (base + 3 < SC_M) v = *(const int4*)(bh + base);
    else { for (int k = 0; k < 4; k++) if (base + k < SC_M) (&v.x)[k] = bh[base + k]; }
    int sum = (v.x + v.y) + (v.z + v.w);
    s[t] = sum;
    __syncthreads();
    for (int o = 1; o < 256; o <<= 1) {
        int x = (t >= o) ? s[t - o] : 0;
        __syncthreads();
        s[t] += x;
        __syncthreads();
    }
    int run = part[blockIdx.x] + s[t] - sum;
    int4 w;
    w.x = run; run += v.x;
    w.y = run; run += v.y;
    w.z = run; run += v.z;
    w.w = run;
    if (base + 3 < SC_M) *(int4*)(bh + base) = w;
    else { for (int k = 0; k < 4; k++) if (base + k < SC_M) bh[base + k] = (&w.x)[k]; }
}

__global__ __launch_bounds__(256) void k_scatter1(const int* __restrict__ src,
                                                  const int* __restrict__ dst,
                                                  const int* __restrict__ bh,
                                                  uint2* __restrict__ tmp) {
    __shared__ int cur[NB2];
    int t = threadIdx.x;
    for (int i = t; i < NB2; i += 256) cur[i] = bh[i * NBLK + blockIdx.x];
    __syncthreads();
    int base = blockIdx.x * EPB;
    for (int i = t; i < EPB; i += 256) {
        int d = dst[base + i];
        int sv = src[base + i];
        int p = atomicAdd(&cur[d >> 8], 1);
        tmp[p] = make_uint2((unsigned)d, (unsigned)sv);
    }
}

// B1: per-bucket node degrees + padded (multiple-of-8) bucket sums
__global__ __launch_bounds__(256) void k_padsum(const uint2* __restrict__ tmp,
                                                const int* __restrict__ bh,
                                                int* __restrict__ degarr,
                                                int* __restrict__ pb) {
    __shared__ int deg[256];
    __shared__ int s[256];
    int b = blockIdx.x, t = threadIdx.x;
    int e0 = bh[b * NBLK];
    int e1 = (b == NB2 - 1) ? N_EDGES : bh[(b + 1) * NBLK];
    deg[t] = 0;
    __syncthreads();
    for (int i = e0 + t; i < e1; i += 256) atomicAdd(&deg[tmp[i].x & 255u], 1);
    __syncthreads();
    int node = b * 256 + t;
    int d = (node < N_NODES) ? deg[t] : 0;
    if (node < N_NODES) degarr[node] = d;
    int dp = (d + 7) & ~7;
    s[t] = dp;
    __syncthreads();
    for (int o = 128; o > 0; o >>= 1) {
        if (t < o) s[t] += s[t + o];
        __syncthreads();
    }
    if (t == 0) pb[b] = s[0];
}

__global__ __launch_bounds__(512) void k_scanP(int* __restrict__ pb) {
    __shared__ int s[512];
    int t = threadIdx.x;
    int v = (t < NB2) ? pb[t] : 0;
    s[t] = v;
    __syncthreads();
    for (int o = 1; o < 512; o <<= 1) {
        int x = (t >= o) ? s[t - o] : 0;
        __syncthreads();
        s[t] += x;
        __syncthreads();
    }
    if (t < NB2) pb[t] = s[t] - v;   // exclusive
}

// B3: padded CSR build (pad slots -> N_NODES = zero row)
__global__ __launch_bounds__(256) void k_build2(const uint2* __restrict__ tmp,
                                                const int* __restrict__ bh,
                                                const int* __restrict__ degarr,
                                                const int* __restrict__ pb,
                                                int* __restrict__ offs,
                                                int* __restrict__ csr) {
    __shared__ int s[256];
    __shared__ int startp[256];
    __shared__ int cur[256];
    int b = blockIdx.x, t = threadIdx.x;
    int e0 = bh[b * NBLK];
    int e1 = (b == NB2 - 1) ? N_EDGES : bh[(b + 1) * NBLK];
    int node = b * 256 + t;
    int d = (node < N_NODES) ? degarr[node] : 0;
    int dp = (d + 7) & ~7;
    s[t] = dp;
    __syncthreads();
    for (int o = 1; o < 256; o <<= 1) {
        int x = (t >= o) ? s[t - o] : 0;
        __syncthreads();
        s[t] += x;
        __syncthreads();
    }
    int st = pb[b] + s[t] - dp;
    startp[t] = st;
    cur[t] = st;
    if (node < N_NODES) {
        offs[node] = st;
        if (node == N_NODES - 1) offs[N_NODES] = st + dp;
    }
    __syncthreads();
    for (int i = e0 + t; i < e1; i += 256) {
        uint2 p = tmp[i];
        int pos = atomicAdd(&cur[p.x & 255u], 1);
        csr[pos] = (int)p.y;
    }
    __syncthreads();
    int end = startp[t] + dp;
    for (int p = cur[t]; p < end; p++) csr[p] = N_NODES;   // zero-row index
}

// ---------------- z = x @ w1a  (128 -> 64, no bias), z stored bf16 ----------------
__global__ __launch_bounds__(256) void k_gemm1(const float* __restrict__ x,
                                               const float* __restrict__ w,
                                               unsigned short* __restrict__ z) {
    __shared__ float ws[D_IN][D];        // 32 KB
    __shared__ float xs[16][D_IN + 1];
    int t = threadIdx.x;
    {
        const float4* w4 = (const float4*)w;
        float4* s4 = (float4*)&ws[0][0];
        for (int i = t; i < (D_IN * D) / 4; i += 256) s4[i] = w4[i];
    }
    int r = t >> 4, c = t & 15;
    __syncthreads();
    for (int base = blockIdx.x * 16; base < N_NODES; base += gridDim.x * 16) {
        for (int i = t; i < 16 * (D_IN / 4); i += 256) {
            int row = i >> 5, k4 = i & 31;
            float4 v = ((const float4*)(x + (size_t)(base + row) * D_IN))[k4];
            xs[row][k4 * 4 + 0] = v.x; xs[row][k4 * 4 + 1] = v.y;
            xs[row][k4 * 4 + 2] = v.z; xs[row][k4 * 4 + 3] = v.w;
        }
        __syncthreads();
        float4 acc = {0.f, 0.f, 0.f, 0.f};
        for (int k = 0; k < D_IN; k++) {
            float xv = xs[r][k];
            float4 wv = *(const float4*)&ws[k][c * 4];
            acc.x += xv * wv.x; acc.y += xv * wv.y;
            acc.z += xv * wv.z; acc.w += xv * wv.w;
        }
        ushort4 p;
        p.x = f2bf(acc.x); p.y = f2bf(acc.y); p.z = f2bf(acc.z); p.w = f2bf(acc.w);
        *(ushort4*)(z + (size_t)(base + r) * D + c * 4) = p;
        __syncthreads();
    }
}

// unconditional padded stride-8 gather: e1-e0 is a multiple of 8; pad rows are zeros
__device__ __forceinline__ void gather8u(float4& acc, const unsigned short* __restrict__ zz,
                                         const int* __restrict__ csr,
                                         int e0, int e1, size_t c4) {
    for (int e = e0; e < e1; e += 8) {
        int4 ia = *(const int4*)(csr + e);
        int4 ib = *(const int4*)(csr + e + 4);
        ushort4 v0 = *(const ushort4*)(zz + (size_t)ia.x * D + c4);
        ushort4 v1 = *(const ushort4*)(zz + (size_t)ia.y * D + c4);
        ushort4 v2 = *(const ushort4*)(zz + (size_t)ia.z * D + c4);
        ushort4 v3 = *(const ushort4*)(zz + (size_t)ia.w * D + c4);
        ushort4 v4 = *(const ushort4*)(zz + (size_t)ib.x * D + c4);
        ushort4 v5 = *(const ushort4*)(zz + (size_t)ib.y * D + c4);
        ushort4 v6 = *(const ushort4*)(zz + (size_t)ib.z * D + c4);
        ushort4 v7 = *(const ushort4*)(zz + (size_t)ib.w * D + c4);
        acc4(acc, v0); acc4(acc, v1); acc4(acc, v2); acc4(acc, v3);
        acc4(acc, v4); acc4(acc, v5); acc4(acc, v6); acc4(acc, v7);
    }
}

// ---------------- conv1 fused: agg(z)+b1a+relu, @w1b+b1b relu, @w2a -> u (bf16) ----------------
__global__ __launch_bounds__(256, 6) void k_conv1(const unsigned short* __restrict__ z,
                                                  const int* __restrict__ offs,
                                                  const int* __restrict__ csr,
                                                  const float* __restrict__ b1a,
                                                  const float* __restrict__ w1b,
                                                  const float* __restrict__ b1b,
                                                  const float* __restrict__ w2a,
                                                  unsigned short* __restrict__ u) {
    __shared__ unsigned short w1s[D][D];   // 8 KB bf16
    __shared__ unsigned short w2s[D][D];   // 8 KB bf16
    __shared__ float h1s[16][D + 1];
    __shared__ float h2s[16][D + 1];
    int t = threadIdx.x;
    int r = t >> 4, c = t & 15;
    {
        for (int i = t; i < (D * D) / 4; i += 256) {
            float4 a = ((const float4*)w1b)[i];
            ushort4 p; p.x = f2bf(a.x); p.y = f2bf(a.y); p.z = f2bf(a.z); p.w = f2bf(a.w);
            *(ushort4*)&(&w1s[0][0])[i * 4] = p;
            float4 b = ((const float4*)w2a)[i];
            ushort4 q; q.x = f2bf(b.x); q.y = f2bf(b.y); q.z = f2bf(b.z); q.w = f2bf(b.w);
            *(ushort4*)&(&w2s[0][0])[i * 4] = q;
        }
    }
    float4 vb1a = ((const float4*)b1a)[c];
    float4 vb1b = ((const float4*)b1b)[c];
    __syncthreads();

    const size_t c4 = (size_t)(c * 4);
    for (int base = blockIdx.x * 16; base < N_NODES; base += gridDim.x * 16) {
        int node = base + r;   // N_NODES % 16 == 0
        float4 acc = {vb1a.x, vb1a.y, vb1a.z, vb1a.w};
        acc4(acc, *(const ushort4*)(z + (size_t)node * D + c4));
        int e0 = offs[node], e1 = offs[node + 1];
        gather8u(acc, z, csr, e0, e1, c4);
        h1s[r][c * 4 + 0] = fmaxf(acc.x, 0.f);
        h1s[r][c * 4 + 1] = fmaxf(acc.y, 0.f);
        h1s[r][c * 4 + 2] = fmaxf(acc.z, 0.f);
        h1s[r][c * 4 + 3] = fmaxf(acc.w, 0.f);
        __syncthreads();
        // --- h2 = relu(h1 @ w1b + b1b) ---
        float4 a2 = vb1b;
        for (int k = 0; k < D; k++) {
            float hv = h1s[r][k];
            ushort4 wv = *(const ushort4*)&w1s[k][c * 4];
            a2.x += hv * bf2f(wv.x); a2.y += hv * bf2f(wv.y);
            a2.z += hv * bf2f(wv.z); a2.w += hv * bf2f(wv.w);
        }
        h2s[r][c * 4 + 0] = fmaxf(a2.x, 0.f);
        h2s[r][c * 4 + 1] = fmaxf(a2.y, 0.f);
        h2s[r][c * 4 + 2] = fmaxf(a2.z, 0.f);
        h2s[r][c * 4 + 3] = fmaxf(a2.w, 0.f);
        __syncthreads();
        // --- u = h2 @ w2a  (bias b2a applied in conv2 agg), u stored bf16 ---
        float4 a3 = {0.f, 0.f, 0.f, 0.f};
        for (int k = 0; k < D; k++) {
            float hv = h2s[r][k];
            ushort4 wv = *(const ushort4*)&w2s[k][c * 4];
            a3.x += hv * bf2f(wv.x); a3.y += hv * bf2f(wv.y);
            a3.z += hv * bf2f(wv.z); a3.w += hv * bf2f(wv.w);
        }
        ushort4 p;
        p.x = f2bf(a3.x); p.y = f2bf(a3.y); p.z = f2bf(a3.z); p.w = f2bf(a3.w);
        *(ushort4*)(u + (size_t)node * D + c4) = p;
        __syncthreads();
    }
}

// ---------------- conv2 fused: agg(u) + b2a + relu -> column sum ----------------
__global__ __launch_bounds__(256) void k_conv2(const unsigned short* __restrict__ u,
                                               const int* __restrict__ offs,
                                               const int* __restrict__ csr,
                                               const float* __restrict__ b2a,
                                               float* __restrict__ colsum) {
    __shared__ float red[16][D + 1];
    int t = threadIdx.x;
    int r = t >> 4, c = t & 15;
    float4 vb = ((const float4*)b2a)[c];
    float4 cs = {0.f, 0.f, 0.f, 0.f};
    const size_t c4 = (size_t)(c * 4);
    for (int base = blockIdx.x * 16; base < N_NODES; base += gridDim.x * 16) {
        int node = base + r;
        float4 acc = {vb.x, vb.y, vb.z, vb.w};
        acc4(acc, *(const ushort4*)(u + (size_t)node * D + c4));
        int e0 = offs[node], e1 = offs[node + 1];
        gather8u(acc, u, csr, e0, e1, c4);
        cs.x += fmaxf(acc.x, 0.f); cs.y += fmaxf(acc.y, 0.f);
        cs.z += fmaxf(acc.z, 0.f); cs.w += fmaxf(acc.w, 0.f);
    }
    red[r][c * 4 + 0] = cs.x; red[r][c * 4 + 1] = cs.y;
    red[r][c * 4 + 2] = cs.z; red[r][c * 4 + 3] = cs.w;
    __syncthreads();
    if (r == 0) {
        float4 tot = {0.f, 0.f, 0.f, 0.f};
        for (int rr = 0; rr < 16; rr++) {
            tot.x += red[rr][c * 4 + 0]; tot.y += red[rr][c * 4 + 1];
            tot.z += red[rr][c * 4 + 2]; tot.w += red[rr][c * 4 + 3];
        }
        atomicAdd(&colsum[c * 4 + 0], tot.x);
        atomicAdd(&colsum[c * 4 + 1], tot.y);
        atomicAdd(&colsum[c * 4 + 2], tot.z);
        atomicAdd(&colsum[c * 4 + 3], tot.w);
    }
}

// ---------------- out = colsum @ w2b + N * b2b ----------------
__global__ void k_final(const float* __restrict__ colsum, const float* __restrict__ w2b,
                        const float* __restrict__ b2b, float* __restrict__ out) {
    int j = threadIdx.x;
    float acc = (float)N_NODES * b2b[j];
    for (int k = 0; k < D; k++) acc += colsum[k] * w2b[k * D + j];
    out[j] = acc;
}

// ---------------- launch ----------------

extern "C" void kernel_launch(void* const* d_in, const int* in_sizes, int n_in,
                              void* d_out, int out_size, void* d_ws, size_t ws_size,
                              hipStream_t stream) {
    const float* x   = (const float*)d_in[0];
    const int*   ei  = (const int*)d_in[1];
    const float* w1a = (const float*)d_in[2];
    const float* b1a = (const float*)d_in[3];
    const float* w1b = (const float*)d_in[4];
    const float* b1b = (const float*)d_in[5];
    const float* w2a = (const float*)d_in[6];
    const float* b2a = (const float*)d_in[7];
    const float* w2b = (const float*)d_in[8];
    const float* b2b = (const float*)d_in[9];
    float* out = (float*)d_out;

    const int* srcp = ei;
    const int* dstp = ei + N_EDGES;

    char* ws = (char*)d_ws;
    unsigned short* z = (unsigned short*)(ws + 0);        // (N+1) rows: 12,800,256 B
    unsigned short* u = (unsigned short*)(ws + 12800256); // 12,800,256 B
    uint2* tmp    = (uint2*)(ws + 25600512);              // 12,800,000 B
    int*   csr    = (int*)(ws + 38400512);                // padded <= 8.2 MB
    int*   bh     = (int*)(ws + 51200512);                // 1,564,000 B
    int*   degarr = (int*)(ws + 52764512);                // 400,000 B
    int*   offs   = (int*)(ws + 53164896);                // 400,064 B
    int*   pb     = (int*)(ws + 53564960);                // 2,048 B
    int*   part   = (int*)(ws + 53567008);                // 2,048 B
    float* colsum = (float*)(ws + 53569056);              // 256 B

    hipMemsetAsync(colsum, 0, D * sizeof(float), stream);
    hipMemsetAsync(z + (size_t)N_NODES * D, 0, D * sizeof(unsigned short), stream);
    hipMemsetAsync(u + (size_t)N_NODES * D, 0, D * sizeof(unsigned short), stream);

    k_hist1   <<<NBLK, 256, 0, stream>>>(dstp, bh);
    k_scanA   <<<SC_NB, 256, 0, stream>>>(bh, part);
    k_scanB   <<<1, 512, 0, stream>>>(part);
    k_scanC   <<<SC_NB, 256, 0, stream>>>(bh, part);
    k_scatter1<<<NBLK, 256, 0, stream>>>(srcp, dstp, bh, tmp);
    k_padsum  <<<NB2, 256, 0, stream>>>(tmp, bh, degarr, pb);
    k_scanP   <<<1, 512, 0, stream>>>(pb);
    k_build2  <<<NB2, 256, 0, stream>>>(tmp, bh, degarr, pb, offs, csr);

    k_gemm1<<<2048, 256, 0, stream>>>(x, w1a, z);
    k_conv1<<<2048, 256, 0, stream>>>(z, offs, csr, b1a, w1b, b1b, w2a, u);
    k_conv2<<<2048, 256, 0, stream>>>(u, offs, csr, b2a, colsum);
    k_final<<<1, 64, 0, stream>>>(colsum, w2b, b2b, out);
}